// Round 8
// baseline (267.598 us; speedup 1.0000x reference)
//
#include <hip/hip_runtime.h>
#include <hip/hip_bf16.h>
#include <math.h>

#define N_NODES 40000
#define N_EDGES 640000
#define IN_DIM 512
#define HID_DIM 128
#define OUT_DIM 40
#define W2_PAD 48    // w2t padded out-cols for MFMA n-tiles (y2 stored at stride 40)
#define SEG 64       // fixed edge-segment slots per row (Poisson(16) max deg ~45)

typedef __attribute__((ext_vector_type(8))) short bf16x8_t;   // 8 bf16 = 4 VGPRs
typedef __attribute__((ext_vector_type(4))) float f32x4_t;    // MFMA accumulator

// fp32 -> bf16 bits, round-to-nearest-even (scalar)
static __device__ __forceinline__ unsigned short f2bf(float f) {
    unsigned u = __float_as_uint(f);
    u += 0x7FFFu + ((u >> 16) & 1u);
    return (unsigned short)(u >> 16);
}
static __device__ __forceinline__ float bflo(unsigned g) { return __uint_as_float(g << 16); }
static __device__ __forceinline__ float bfhi(unsigned g) { return __uint_as_float(g & 0xFFFF0000u); }

// ---------------- fused: zero cursor + weight conversion ----------------
// W1 [512x128] -> w1t bf16 [128][512] (transposed); W2 [128x40] -> w2t bf16 [48][128]
__global__ __launch_bounds__(256) void convert_zero_kernel(const float* __restrict__ W1,
                                                           const float* __restrict__ W2,
                                                           unsigned short* __restrict__ w1t,
                                                           unsigned short* __restrict__ w2t,
                                                           int* __restrict__ cursor) {
    int idx = blockIdx.x * 256 + threadIdx.x;
    if (idx < N_NODES / 4) {
        reinterpret_cast<int4*>(cursor)[idx] = make_int4(0, 0, 0, 0);
    }
    if (idx < IN_DIM * HID_DIM) {
        int k = idx >> 7;
        int n = idx & 127;
        w1t[n * IN_DIM + k] = f2bf(W1[idx]);
    } else if (idx < IN_DIM * HID_DIM + W2_PAD * HID_DIM) {
        int j = idx - IN_DIM * HID_DIM;
        int n = j >> 7;          // padded out-col 0..47
        int k = j & 127;
        w2t[n * HID_DIM + k] = (n < OUT_DIM) ? f2bf(W2[k * OUT_DIM + n]) : 0;
    }
}

// ---------------- scatter edges into fixed-stride row segments ----------------
// pos = row*SEG + cursor[row]++; packed meta: col(u16) | bf16(val)<<16.
// cursor[row] ends as the row's edge count.
__global__ __launch_bounds__(256) void scatter_kernel(const int* __restrict__ erow,
                                                      const int* __restrict__ ecol,
                                                      const float* __restrict__ eval,
                                                      int* __restrict__ cursor,
                                                      unsigned* __restrict__ sortedP) {
    int e = blockIdx.x * 256 + threadIdx.x;
    if (e < N_EDGES) {
        int r = erow[e];
        int pos = atomicAdd(&cursor[r], 1);
        sortedP[r * SEG + pos] = (unsigned)ecol[e] | ((unsigned)f2bf(eval[e]) << 16);
    }
}

// ---------------- GEMM1 (MFMA bf16, LDS-free): y1b = bf16(x @ W1) ----------------
// No LDS, no barriers. Wave w of block owns rows m0+w*16..+15 exclusively:
// A-frag (m=lane&15, k=quad*8+j) loaded straight from x and converted in-register;
// B-frags straight from L2-resident w1t [n][k] (n=lane&15, k=quad*8+j).
__global__ __launch_bounds__(256) void gemm1_mfma_kernel(const float* __restrict__ x,
                                                         const unsigned short* __restrict__ w1t,
                                                         unsigned short* __restrict__ y1b) {
    const int t    = threadIdx.x;
    const int wave = t >> 6;
    const int lane = t & 63;
    const int mrow = lane & 15;
    const int quad = lane >> 4;
    const int row  = blockIdx.x * 64 + wave * 16 + mrow;

    const float* xrow = &x[(size_t)row * IN_DIM + quad * 8];
    const unsigned short* wb = &w1t[(size_t)mrow * IN_DIM + quad * 8];

    f32x4_t acc[8];
#pragma unroll
    for (int i = 0; i < 8; ++i) acc[i] = (f32x4_t){0.f, 0.f, 0.f, 0.f};

    for (int k0 = 0; k0 < IN_DIM; k0 += 32) {
        float4 xa = *reinterpret_cast<const float4*>(xrow + k0);
        float4 xb = *reinterpret_cast<const float4*>(xrow + k0 + 4);
        union { bf16x8_t v; __hip_bfloat162 b[4]; } pa;
        pa.b[0] = __float22bfloat162_rn(make_float2(xa.x, xa.y));
        pa.b[1] = __float22bfloat162_rn(make_float2(xa.z, xa.w));
        pa.b[2] = __float22bfloat162_rn(make_float2(xb.x, xb.y));
        pa.b[3] = __float22bfloat162_rn(make_float2(xb.z, xb.w));
#pragma unroll
        for (int nt = 0; nt < 8; ++nt) {
            bf16x8_t b = *reinterpret_cast<const bf16x8_t*>(wb + (size_t)nt * 16 * IN_DIM + k0);
            acc[nt] = __builtin_amdgcn_mfma_f32_16x16x32_bf16(pa.v, b, acc[nt], 0, 0, 0);
        }
    }

    // C/D layout: col = lane&15, row = quad*4 + reg
    const int m0 = blockIdx.x * 64 + wave * 16;
#pragma unroll
    for (int nt = 0; nt < 8; ++nt) {
#pragma unroll
        for (int reg = 0; reg < 4; ++reg) {
            int orow = m0 + quad * 4 + reg;
            y1b[(size_t)orow * HID_DIM + nt * 16 + mrow] = f2bf(acc[nt][reg]);
        }
    }
}

// ---------------- SpMM1: h[row] = relu(sum val*y1[col] + b1), bf16 out ----------------
// One wave per row, single fixed 64-slot segment (no outer loop). Quarter-wave per
// edge: lane = (edge q = lane>>4, feat grp fl = lane&15), one dwordx4 (8 bf16 feats)
// per lane per edge, 8 edges per step, packed meta (1 shfl/edge). Lanes >= cnt hold
// meta 0 -> col 0, val +0.0f (contributes nothing).
__global__ __launch_bounds__(256) void spmm1_kernel(const int* __restrict__ counts,
                                                    const unsigned* __restrict__ sortedP,
                                                    const unsigned short* __restrict__ y1b,
                                                    const float* __restrict__ b1,
                                                    unsigned short* __restrict__ h_bf) {
    const int lane = threadIdx.x & 63;
    const int q    = lane >> 4;
    const int fl   = lane & 15;
    const int row  = blockIdx.x * 4 + (threadIdx.x >> 6);
    const int cnt  = counts[row];
    unsigned meta  = (lane < cnt) ? sortedP[row * SEG + lane] : 0u;
    float a[8] = {0.f, 0.f, 0.f, 0.f, 0.f, 0.f, 0.f, 0.f};

    for (int j = 0; j < cnt; j += 8) {
        unsigned p0 = (unsigned)__shfl((int)meta, j + q, 64);
        unsigned p1 = (unsigned)__shfl((int)meta, j + 4 + q, 64);
        float v0 = __uint_as_float(p0 & 0xFFFF0000u);
        float v1 = __uint_as_float(p1 & 0xFFFF0000u);
        int   c0 = p0 & 0xFFFF;
        int   c1 = p1 & 0xFFFF;
        uint4 g0 = *reinterpret_cast<const uint4*>(&y1b[(size_t)c0 * HID_DIM + fl * 8]);
        uint4 g1 = *reinterpret_cast<const uint4*>(&y1b[(size_t)c1 * HID_DIM + fl * 8]);
        a[0] += v0 * bflo(g0.x); a[1] += v0 * bfhi(g0.x);
        a[2] += v0 * bflo(g0.y); a[3] += v0 * bfhi(g0.y);
        a[4] += v0 * bflo(g0.z); a[5] += v0 * bfhi(g0.z);
        a[6] += v0 * bflo(g0.w); a[7] += v0 * bfhi(g0.w);
        a[0] += v1 * bflo(g1.x); a[1] += v1 * bfhi(g1.x);
        a[2] += v1 * bflo(g1.y); a[3] += v1 * bfhi(g1.y);
        a[4] += v1 * bflo(g1.z); a[5] += v1 * bfhi(g1.z);
        a[6] += v1 * bflo(g1.w); a[7] += v1 * bfhi(g1.w);
    }
    // combine the four quarter-wave partials
#pragma unroll
    for (int i = 0; i < 8; ++i) {
        a[i] += __shfl_xor(a[i], 16, 64);
        a[i] += __shfl_xor(a[i], 32, 64);
    }
    if (q == 0) {
        float4 vb0 = *reinterpret_cast<const float4*>(&b1[fl * 8]);
        float4 vb1 = *reinterpret_cast<const float4*>(&b1[fl * 8 + 4]);
        union { uint4 v; __hip_bfloat162 b[4]; } pk;
        pk.b[0] = __float22bfloat162_rn(make_float2(fmaxf(a[0] + vb0.x, 0.f), fmaxf(a[1] + vb0.y, 0.f)));
        pk.b[1] = __float22bfloat162_rn(make_float2(fmaxf(a[2] + vb0.z, 0.f), fmaxf(a[3] + vb0.w, 0.f)));
        pk.b[2] = __float22bfloat162_rn(make_float2(fmaxf(a[4] + vb1.x, 0.f), fmaxf(a[5] + vb1.y, 0.f)));
        pk.b[3] = __float22bfloat162_rn(make_float2(fmaxf(a[6] + vb1.z, 0.f), fmaxf(a[7] + vb1.w, 0.f)));
        *reinterpret_cast<uint4*>(&h_bf[(size_t)row * HID_DIM + fl * 8]) = pk.v;
    }
}

// ---------------- GEMM2 (MFMA bf16, LDS-free): y2 = bf16(h @ W2), stride 40 ----------------
__global__ __launch_bounds__(256) void gemm2_mfma_kernel(const unsigned short* __restrict__ h_bf,
                                                         const unsigned short* __restrict__ w2t,
                                                         unsigned short* __restrict__ y2) {
    const int t    = threadIdx.x;
    const int wave = t >> 6;
    const int lane = t & 63;
    const int mrow = lane & 15;
    const int quad = lane >> 4;
    const int row  = blockIdx.x * 64 + wave * 16 + mrow;

    const unsigned short* hrow = &h_bf[(size_t)row * HID_DIM + quad * 8];
    const unsigned short* wb   = &w2t[(size_t)mrow * HID_DIM + quad * 8];

    f32x4_t acc[3];
#pragma unroll
    for (int i = 0; i < 3; ++i) acc[i] = (f32x4_t){0.f, 0.f, 0.f, 0.f};
#pragma unroll
    for (int k0 = 0; k0 < HID_DIM; k0 += 32) {
        bf16x8_t a = *reinterpret_cast<const bf16x8_t*>(hrow + k0);
#pragma unroll
        for (int nt = 0; nt < 3; ++nt) {
            bf16x8_t b = *reinterpret_cast<const bf16x8_t*>(wb + (size_t)nt * 16 * HID_DIM + k0);
            acc[nt] = __builtin_amdgcn_mfma_f32_16x16x32_bf16(a, b, acc[nt], 0, 0, 0);
        }
    }
    const int m0 = blockIdx.x * 64 + wave * 16;
#pragma unroll
    for (int nt = 0; nt < 3; ++nt) {
        int col = nt * 16 + mrow;
        if (col < OUT_DIM) {
#pragma unroll
            for (int reg = 0; reg < 4; ++reg) {
                int orow = m0 + quad * 4 + reg;
                y2[(size_t)orow * OUT_DIM + col] = f2bf(acc[nt][reg]);
            }
        }
    }
}

// ---------------- SpMM2 + bias + log_softmax fused ----------------
// Single fixed segment; quarter-wave per edge, lanes fl<10 load dwordx2 (4 feats).
__global__ __launch_bounds__(256) void spmm2_lsm_kernel(const int* __restrict__ counts,
                                                        const unsigned* __restrict__ sortedP,
                                                        const unsigned short* __restrict__ y2,
                                                        const float* __restrict__ b2,
                                                        float* __restrict__ out) {
    const int lane = threadIdx.x & 63;
    const int q    = lane >> 4;
    const int fl   = lane & 15;
    const bool act = fl < 10;                 // feats fl*4 .. fl*4+3
    const int row  = blockIdx.x * 4 + (threadIdx.x >> 6);
    const int cnt  = counts[row];
    unsigned meta  = (lane < cnt) ? sortedP[row * SEG + lane] : 0u;
    float a[4] = {0.f, 0.f, 0.f, 0.f};

    for (int j = 0; j < cnt; j += 8) {
        unsigned p0 = (unsigned)__shfl((int)meta, j + q, 64);
        unsigned p1 = (unsigned)__shfl((int)meta, j + 4 + q, 64);
        if (act) {
            float v0 = __uint_as_float(p0 & 0xFFFF0000u);
            float v1 = __uint_as_float(p1 & 0xFFFF0000u);
            int   c0 = p0 & 0xFFFF;
            int   c1 = p1 & 0xFFFF;
            uint2 g0 = *reinterpret_cast<const uint2*>(&y2[(size_t)c0 * OUT_DIM + fl * 4]);
            uint2 g1 = *reinterpret_cast<const uint2*>(&y2[(size_t)c1 * OUT_DIM + fl * 4]);
            a[0] += v0 * bflo(g0.x); a[1] += v0 * bfhi(g0.x);
            a[2] += v0 * bflo(g0.y); a[3] += v0 * bfhi(g0.y);
            a[0] += v1 * bflo(g1.x); a[1] += v1 * bfhi(g1.x);
            a[2] += v1 * bflo(g1.y); a[3] += v1 * bfhi(g1.y);
        }
    }
#pragma unroll
    for (int i = 0; i < 4; ++i) {
        a[i] += __shfl_xor(a[i], 16, 64);
        a[i] += __shfl_xor(a[i], 32, 64);
    }
    float val[4];
    float ml = -INFINITY;
    if (act) {
        float4 vb = *reinterpret_cast<const float4*>(&b2[fl * 4]);
        val[0] = a[0] + vb.x; val[1] = a[1] + vb.y;
        val[2] = a[2] + vb.z; val[3] = a[3] + vb.w;
        ml = fmaxf(fmaxf(val[0], val[1]), fmaxf(val[2], val[3]));
    }
#pragma unroll
    for (int off = 1; off < 16; off <<= 1) ml = fmaxf(ml, __shfl_xor(ml, off, 64));
    float sl = 0.f;
    if (act) sl = expf(val[0] - ml) + expf(val[1] - ml) + expf(val[2] - ml) + expf(val[3] - ml);
#pragma unroll
    for (int off = 1; off < 16; off <<= 1) sl += __shfl_xor(sl, off, 64);
    if (act && q == 0) {
        float lg = logf(sl);
        float4 o = make_float4(val[0] - ml - lg, val[1] - ml - lg,
                               val[2] - ml - lg, val[3] - ml - lg);
        *reinterpret_cast<float4*>(&out[(size_t)row * OUT_DIM + fl * 4]) = o;
    }
}

extern "C" void kernel_launch(void* const* d_in, const int* in_sizes, int n_in,
                              void* d_out, int out_size, void* d_ws, size_t ws_size,
                              hipStream_t stream) {
    const float* x    = (const float*)d_in[0];
    const int*   erow = (const int*)d_in[1];
    const int*   ecol = (const int*)d_in[2];
    const float* eval = (const float*)d_in[3];
    const float* W1   = (const float*)d_in[4];
    const float* b1   = (const float*)d_in[5];
    const float* W2   = (const float*)d_in[6];
    const float* b2   = (const float*)d_in[7];
    float* out = (float*)d_out;

    // workspace layout (16B-aligned regions)
    char* p = (char*)d_ws;
    unsigned short* h_bf = (unsigned short*)p; p += (size_t)N_NODES * HID_DIM * 2;  // 10.24 MB
    unsigned* sortedP = (unsigned*)p;          p += (size_t)N_NODES * SEG * 4;      // 10.24 MB
    unsigned short* y1b = (unsigned short*)p;  p += (size_t)N_NODES * HID_DIM * 2;  // 10.24 MB
    unsigned short* y2  = (unsigned short*)p;  p += (size_t)N_NODES * OUT_DIM * 2;  // 3.2 MB
    int*   cursor    = (int*)p;                p += (size_t)N_NODES * 4;            // counts after scatter
    unsigned short* w1t = (unsigned short*)p;  p += (size_t)HID_DIM * IN_DIM * 2;   // 128 KB
    unsigned short* w2t = (unsigned short*)p;                                       // 12.3 KB

    // prep: zero cursor + convert weights (one launch)
    convert_zero_kernel<<<(IN_DIM * HID_DIM + W2_PAD * HID_DIM + 255) / 256, 256, 0, stream>>>(
        W1, W2, w1t, w2t, cursor);
    // edge scatter into fixed segments (cursor becomes per-row count)
    scatter_kernel<<<(N_EDGES + 255) / 256, 256, 0, stream>>>(erow, ecol, eval, cursor, sortedP);

    // layer 1
    gemm1_mfma_kernel<<<N_NODES / 64, 256, 0, stream>>>(x, w1t, y1b);
    spmm1_kernel<<<N_NODES / 4, 256, 0, stream>>>(cursor, sortedP, y1b, b1, h_bf);

    // layer 2 (+ fused bias + log_softmax)
    gemm2_mfma_kernel<<<N_NODES / 64, 256, 0, stream>>>(h_bf, w2t, y2);
    spmm2_lsm_kernel<<<N_NODES / 4, 256, 0, stream>>>(cursor, sortedP, y2, b2, out);
}

// Round 9
// 235.655 us; speedup vs baseline: 1.1355x; 1.1355x over previous
//
#include <hip/hip_runtime.h>
#include <hip/hip_bf16.h>
#include <math.h>

#define N_NODES 40000
#define N_EDGES 640000
#define IN_DIM 512
#define HID_DIM 128
#define OUT_DIM 40
#define W2_PAD 48    // w2t padded out-cols for MFMA n-tiles (y2 stored at stride 40)
#define SEG 64       // fixed edge-segment slots per row (Poisson(16) max deg ~45)

typedef __attribute__((ext_vector_type(8))) short bf16x8_t;   // 8 bf16 = 4 VGPRs
typedef __attribute__((ext_vector_type(4))) float f32x4_t;    // MFMA accumulator

// fp32 -> bf16 bits, round-to-nearest-even (scalar)
static __device__ __forceinline__ unsigned short f2bf(float f) {
    unsigned u = __float_as_uint(f);
    u += 0x7FFFu + ((u >> 16) & 1u);
    return (unsigned short)(u >> 16);
}
static __device__ __forceinline__ float bflo(unsigned g) { return __uint_as_float(g << 16); }
static __device__ __forceinline__ float bfhi(unsigned g) { return __uint_as_float(g & 0xFFFF0000u); }

// ---------------- fused: zero cursor + weight conversion ----------------
// W1 [512x128] -> w1t bf16 [128][512] (transposed); W2 [128x40] -> w2t bf16 [48][128]
__global__ __launch_bounds__(256) void convert_zero_kernel(const float* __restrict__ W1,
                                                           const float* __restrict__ W2,
                                                           unsigned short* __restrict__ w1t,
                                                           unsigned short* __restrict__ w2t,
                                                           int* __restrict__ cursor) {
    int idx = blockIdx.x * 256 + threadIdx.x;
    if (idx < N_NODES / 4) {
        reinterpret_cast<int4*>(cursor)[idx] = make_int4(0, 0, 0, 0);
    }
    if (idx < IN_DIM * HID_DIM) {
        int k = idx >> 7;
        int n = idx & 127;
        w1t[n * IN_DIM + k] = f2bf(W1[idx]);
    } else if (idx < IN_DIM * HID_DIM + W2_PAD * HID_DIM) {
        int j = idx - IN_DIM * HID_DIM;
        int n = j >> 7;          // padded out-col 0..47
        int k = j & 127;
        w2t[n * HID_DIM + k] = (n < OUT_DIM) ? f2bf(W2[k * OUT_DIM + n]) : 0;
    }
}

// ---------------- scatter edges into fixed-stride row segments ----------------
// pos = row*SEG + cursor[row]++; packed meta: col(u16) | bf16(val)<<16.
// cursor[row] ends as the row's edge count.
__global__ __launch_bounds__(256) void scatter_kernel(const int* __restrict__ erow,
                                                      const int* __restrict__ ecol,
                                                      const float* __restrict__ eval,
                                                      int* __restrict__ cursor,
                                                      unsigned* __restrict__ sortedP) {
    int e = blockIdx.x * 256 + threadIdx.x;
    if (e < N_EDGES) {
        int r = erow[e];
        int pos = atomicAdd(&cursor[r], 1);
        sortedP[r * SEG + pos] = (unsigned)ecol[e] | ((unsigned)f2bf(eval[e]) << 16);
    }
}

// ---------------- GEMM1 (MFMA bf16, LDS + register-prefetch pipeline) ----------------
// 64 rows x 128 cols per block, BK=32; next k-tile prefetched into registers
// after the barrier so global loads overlap the MFMA+ds_read section.
__global__ __launch_bounds__(256) void gemm1_mfma_kernel(const float* __restrict__ x,
                                                         const unsigned short* __restrict__ w1t,
                                                         unsigned short* __restrict__ y1b) {
    __shared__ unsigned short Al[64][40];    // A tile: 64 rows x 32 k (pad 40)
    __shared__ unsigned short Bl[128][40];   // B^T tile: 128 cols x 32 k
    const int t    = threadIdx.x;
    const int wave = t >> 6;
    const int lane = t & 63;
    const int m0   = blockIdx.x * 64;
    const int mrow = lane & 15;
    const int quad = lane >> 4;

    const int ar = t >> 2;                   // A staging row
    const int ac = (t & 3) * 8;              // A staging k-offset
    const float* xptr = &x[(size_t)(m0 + ar) * IN_DIM + ac];
    const unsigned short* bptr0 = &w1t[(size_t)(t >> 2) * IN_DIM + (t & 3) * 8];
    const unsigned short* bptr1 = bptr0 + (size_t)64 * IN_DIM;

    f32x4_t acc[8];
#pragma unroll
    for (int i = 0; i < 8; ++i) acc[i] = (f32x4_t){0.f, 0.f, 0.f, 0.f};

    // prologue: prefetch k0 = 0
    float4 xa = *reinterpret_cast<const float4*>(xptr);
    float4 xb = *reinterpret_cast<const float4*>(xptr + 4);
    int4   bw0 = *reinterpret_cast<const int4*>(bptr0);
    int4   bw1 = *reinterpret_cast<const int4*>(bptr1);

    for (int k0 = 0; k0 < IN_DIM; k0 += 32) {
        // stage current registers into LDS
        {
            union { int4 v; __hip_bfloat162 b[4]; } pk;
            pk.b[0] = __float22bfloat162_rn(make_float2(xa.x, xa.y));
            pk.b[1] = __float22bfloat162_rn(make_float2(xa.z, xa.w));
            pk.b[2] = __float22bfloat162_rn(make_float2(xb.x, xb.y));
            pk.b[3] = __float22bfloat162_rn(make_float2(xb.z, xb.w));
            *reinterpret_cast<int4*>(&Al[ar][ac]) = pk.v;
            *reinterpret_cast<int4*>(&Bl[t >> 2][(t & 3) * 8]) = bw0;
            *reinterpret_cast<int4*>(&Bl[64 + (t >> 2)][(t & 3) * 8]) = bw1;
        }
        __syncthreads();

        // prefetch next k-tile (overlaps the MFMA section below)
        if (k0 + 32 < IN_DIM) {
            xa  = *reinterpret_cast<const float4*>(xptr + k0 + 32);
            xb  = *reinterpret_cast<const float4*>(xptr + k0 + 36);
            bw0 = *reinterpret_cast<const int4*>(bptr0 + k0 + 32);
            bw1 = *reinterpret_cast<const int4*>(bptr1 + k0 + 32);
        }

        bf16x8_t a = *reinterpret_cast<const bf16x8_t*>(&Al[wave * 16 + mrow][quad * 8]);
#pragma unroll
        for (int nt = 0; nt < 8; ++nt) {
            bf16x8_t b = *reinterpret_cast<const bf16x8_t*>(&Bl[nt * 16 + mrow][quad * 8]);
            acc[nt] = __builtin_amdgcn_mfma_f32_16x16x32_bf16(a, b, acc[nt], 0, 0, 0);
        }
        __syncthreads();
    }

    // C/D layout: col = lane&15, row = quad*4 + reg
#pragma unroll
    for (int nt = 0; nt < 8; ++nt) {
#pragma unroll
        for (int reg = 0; reg < 4; ++reg) {
            int row = m0 + wave * 16 + quad * 4 + reg;
            y1b[(size_t)row * HID_DIM + nt * 16 + mrow] = f2bf(acc[nt][reg]);
        }
    }
}

// ---------------- SpMM1: h[row] = relu(sum val*y1[col] + b1), bf16 out ----------------
// One wave per row, single fixed 64-slot segment (no outer loop). Quarter-wave per
// edge: lane = (edge q = lane>>4, feat grp fl = lane&15), one dwordx4 (8 bf16 feats)
// per lane per edge, 8 edges per step, packed meta (1 shfl/edge). Lanes >= cnt hold
// meta 0 -> col 0, val +0.0f (contributes nothing).
__global__ __launch_bounds__(256) void spmm1_kernel(const int* __restrict__ counts,
                                                    const unsigned* __restrict__ sortedP,
                                                    const unsigned short* __restrict__ y1b,
                                                    const float* __restrict__ b1,
                                                    unsigned short* __restrict__ h_bf) {
    const int lane = threadIdx.x & 63;
    const int q    = lane >> 4;
    const int fl   = lane & 15;
    const int row  = blockIdx.x * 4 + (threadIdx.x >> 6);
    const int cnt  = counts[row];
    unsigned meta  = (lane < cnt) ? sortedP[row * SEG + lane] : 0u;
    float a[8] = {0.f, 0.f, 0.f, 0.f, 0.f, 0.f, 0.f, 0.f};

    for (int j = 0; j < cnt; j += 8) {
        unsigned p0 = (unsigned)__shfl((int)meta, j + q, 64);
        unsigned p1 = (unsigned)__shfl((int)meta, j + 4 + q, 64);
        float v0 = __uint_as_float(p0 & 0xFFFF0000u);
        float v1 = __uint_as_float(p1 & 0xFFFF0000u);
        int   c0 = p0 & 0xFFFF;
        int   c1 = p1 & 0xFFFF;
        uint4 g0 = *reinterpret_cast<const uint4*>(&y1b[(size_t)c0 * HID_DIM + fl * 8]);
        uint4 g1 = *reinterpret_cast<const uint4*>(&y1b[(size_t)c1 * HID_DIM + fl * 8]);
        a[0] += v0 * bflo(g0.x); a[1] += v0 * bfhi(g0.x);
        a[2] += v0 * bflo(g0.y); a[3] += v0 * bfhi(g0.y);
        a[4] += v0 * bflo(g0.z); a[5] += v0 * bfhi(g0.z);
        a[6] += v0 * bflo(g0.w); a[7] += v0 * bfhi(g0.w);
        a[0] += v1 * bflo(g1.x); a[1] += v1 * bfhi(g1.x);
        a[2] += v1 * bflo(g1.y); a[3] += v1 * bfhi(g1.y);
        a[4] += v1 * bflo(g1.z); a[5] += v1 * bfhi(g1.z);
        a[6] += v1 * bflo(g1.w); a[7] += v1 * bfhi(g1.w);
    }
    // combine the four quarter-wave partials
#pragma unroll
    for (int i = 0; i < 8; ++i) {
        a[i] += __shfl_xor(a[i], 16, 64);
        a[i] += __shfl_xor(a[i], 32, 64);
    }
    if (q == 0) {
        float4 vb0 = *reinterpret_cast<const float4*>(&b1[fl * 8]);
        float4 vb1 = *reinterpret_cast<const float4*>(&b1[fl * 8 + 4]);
        union { uint4 v; __hip_bfloat162 b[4]; } pk;
        pk.b[0] = __float22bfloat162_rn(make_float2(fmaxf(a[0] + vb0.x, 0.f), fmaxf(a[1] + vb0.y, 0.f)));
        pk.b[1] = __float22bfloat162_rn(make_float2(fmaxf(a[2] + vb0.z, 0.f), fmaxf(a[3] + vb0.w, 0.f)));
        pk.b[2] = __float22bfloat162_rn(make_float2(fmaxf(a[4] + vb1.x, 0.f), fmaxf(a[5] + vb1.y, 0.f)));
        pk.b[3] = __float22bfloat162_rn(make_float2(fmaxf(a[6] + vb1.z, 0.f), fmaxf(a[7] + vb1.w, 0.f)));
        *reinterpret_cast<uint4*>(&h_bf[(size_t)row * HID_DIM + fl * 8]) = pk.v;
    }
}

// ---------------- GEMM2 (MFMA bf16, LDS): y2 = bf16(h @ W2)  (40000x128 @ 128x40, stride 40) ----------------
__global__ __launch_bounds__(256) void gemm2_mfma_kernel(const unsigned short* __restrict__ h_bf,
                                                         const unsigned short* __restrict__ w2t,
                                                         unsigned short* __restrict__ y2) {
    __shared__ unsigned short Hs[64][136];   // 64 rows x 128 k (pad 136)
    __shared__ unsigned short Ws[W2_PAD][136];
    const int t    = threadIdx.x;
    const int wave = t >> 6;
    const int lane = t & 63;
    const int m0   = blockIdx.x * 64;
    const int mrow = lane & 15;
    const int quad = lane >> 4;

#pragma unroll
    for (int i = 0; i < 4; ++i) {               // 1024 16B chunks of H
        int flat = i * 256 + t;
        int r = flat >> 4;
        int c = (flat & 15) * 8;
        *reinterpret_cast<int4*>(&Hs[r][c]) =
            *reinterpret_cast<const int4*>(&h_bf[(size_t)(m0 + r) * HID_DIM + c]);
    }
#pragma unroll
    for (int i = 0; i < 3; ++i) {               // 768 16B chunks of W
        int flat = i * 256 + t;
        int n = flat >> 4;
        int c = (flat & 15) * 8;
        *reinterpret_cast<int4*>(&Ws[n][c]) =
            *reinterpret_cast<const int4*>(&w2t[(size_t)n * HID_DIM + c]);
    }
    __syncthreads();

    f32x4_t acc[3];
#pragma unroll
    for (int i = 0; i < 3; ++i) acc[i] = (f32x4_t){0.f, 0.f, 0.f, 0.f};
#pragma unroll
    for (int k0 = 0; k0 < HID_DIM; k0 += 32) {
        bf16x8_t a = *reinterpret_cast<const bf16x8_t*>(&Hs[wave * 16 + mrow][k0 + quad * 8]);
#pragma unroll
        for (int nt = 0; nt < 3; ++nt) {
            bf16x8_t b = *reinterpret_cast<const bf16x8_t*>(&Ws[nt * 16 + mrow][k0 + quad * 8]);
            acc[nt] = __builtin_amdgcn_mfma_f32_16x16x32_bf16(a, b, acc[nt], 0, 0, 0);
        }
    }
#pragma unroll
    for (int nt = 0; nt < 3; ++nt) {
        int col = nt * 16 + mrow;
        if (col < OUT_DIM) {
#pragma unroll
            for (int reg = 0; reg < 4; ++reg) {
                int row = m0 + wave * 16 + quad * 4 + reg;
                y2[(size_t)row * OUT_DIM + col] = f2bf(acc[nt][reg]);
            }
        }
    }
}

// ---------------- SpMM2 + bias + log_softmax fused ----------------
// Single fixed segment; quarter-wave per edge, lanes fl<10 load dwordx2 (4 feats).
__global__ __launch_bounds__(256) void spmm2_lsm_kernel(const int* __restrict__ counts,
                                                        const unsigned* __restrict__ sortedP,
                                                        const unsigned short* __restrict__ y2,
                                                        const float* __restrict__ b2,
                                                        float* __restrict__ out) {
    const int lane = threadIdx.x & 63;
    const int q    = lane >> 4;
    const int fl   = lane & 15;
    const bool act = fl < 10;                 // feats fl*4 .. fl*4+3
    const int row  = blockIdx.x * 4 + (threadIdx.x >> 6);
    const int cnt  = counts[row];
    unsigned meta  = (lane < cnt) ? sortedP[row * SEG + lane] : 0u;
    float a[4] = {0.f, 0.f, 0.f, 0.f};

    for (int j = 0; j < cnt; j += 8) {
        unsigned p0 = (unsigned)__shfl((int)meta, j + q, 64);
        unsigned p1 = (unsigned)__shfl((int)meta, j + 4 + q, 64);
        if (act) {
            float v0 = __uint_as_float(p0 & 0xFFFF0000u);
            float v1 = __uint_as_float(p1 & 0xFFFF0000u);
            int   c0 = p0 & 0xFFFF;
            int   c1 = p1 & 0xFFFF;
            uint2 g0 = *reinterpret_cast<const uint2*>(&y2[(size_t)c0 * OUT_DIM + fl * 4]);
            uint2 g1 = *reinterpret_cast<const uint2*>(&y2[(size_t)c1 * OUT_DIM + fl * 4]);
            a[0] += v0 * bflo(g0.x); a[1] += v0 * bfhi(g0.x);
            a[2] += v0 * bflo(g0.y); a[3] += v0 * bfhi(g0.y);
            a[0] += v1 * bflo(g1.x); a[1] += v1 * bfhi(g1.x);
            a[2] += v1 * bflo(g1.y); a[3] += v1 * bfhi(g1.y);
        }
    }
#pragma unroll
    for (int i = 0; i < 4; ++i) {
        a[i] += __shfl_xor(a[i], 16, 64);
        a[i] += __shfl_xor(a[i], 32, 64);
    }
    float val[4];
    float ml = -INFINITY;
    if (act) {
        float4 vb = *reinterpret_cast<const float4*>(&b2[fl * 4]);
        val[0] = a[0] + vb.x; val[1] = a[1] + vb.y;
        val[2] = a[2] + vb.z; val[3] = a[3] + vb.w;
        ml = fmaxf(fmaxf(val[0], val[1]), fmaxf(val[2], val[3]));
    }
#pragma unroll
    for (int off = 1; off < 16; off <<= 1) ml = fmaxf(ml, __shfl_xor(ml, off, 64));
    float sl = 0.f;
    if (act) sl = expf(val[0] - ml) + expf(val[1] - ml) + expf(val[2] - ml) + expf(val[3] - ml);
#pragma unroll
    for (int off = 1; off < 16; off <<= 1) sl += __shfl_xor(sl, off, 64);
    if (act && q == 0) {
        float lg = logf(sl);
        float4 o = make_float4(val[0] - ml - lg, val[1] - ml - lg,
                               val[2] - ml - lg, val[3] - ml - lg);
        *reinterpret_cast<float4*>(&out[(size_t)row * OUT_DIM + fl * 4]) = o;
    }
}

extern "C" void kernel_launch(void* const* d_in, const int* in_sizes, int n_in,
                              void* d_out, int out_size, void* d_ws, size_t ws_size,
                              hipStream_t stream) {
    const float* x    = (const float*)d_in[0];
    const int*   erow = (const int*)d_in[1];
    const int*   ecol = (const int*)d_in[2];
    const float* eval = (const float*)d_in[3];
    const float* W1   = (const float*)d_in[4];
    const float* b1   = (const float*)d_in[5];
    const float* W2   = (const float*)d_in[6];
    const float* b2   = (const float*)d_in[7];
    float* out = (float*)d_out;

    // workspace layout (16B-aligned regions)
    char* p = (char*)d_ws;
    unsigned short* h_bf = (unsigned short*)p; p += (size_t)N_NODES * HID_DIM * 2;  // 10.24 MB
    unsigned* sortedP = (unsigned*)p;          p += (size_t)N_NODES * SEG * 4;      // 10.24 MB
    unsigned short* y1b = (unsigned short*)p;  p += (size_t)N_NODES * HID_DIM * 2;  // 10.24 MB
    unsigned short* y2  = (unsigned short*)p;  p += (size_t)N_NODES * OUT_DIM * 2;  // 3.2 MB
    int*   cursor    = (int*)p;                p += (size_t)N_NODES * 4;            // counts after scatter
    unsigned short* w1t = (unsigned short*)p;  p += (size_t)HID_DIM * IN_DIM * 2;   // 128 KB
    unsigned short* w2t = (unsigned short*)p;                                       // 12.3 KB

    // prep: zero cursor + convert weights (one launch)
    convert_zero_kernel<<<(IN_DIM * HID_DIM + W2_PAD * HID_DIM + 255) / 256, 256, 0, stream>>>(
        W1, W2, w1t, w2t, cursor);
    // edge scatter into fixed segments (cursor becomes per-row count)
    scatter_kernel<<<(N_EDGES + 255) / 256, 256, 0, stream>>>(erow, ecol, eval, cursor, sortedP);

    // layer 1
    gemm1_mfma_kernel<<<N_NODES / 64, 256, 0, stream>>>(x, w1t, y1b);
    spmm1_kernel<<<N_NODES / 4, 256, 0, stream>>>(cursor, sortedP, y1b, b1, h_bf);

    // layer 2 (+ fused bias + log_softmax)
    gemm2_mfma_kernel<<<N_NODES / 64, 256, 0, stream>>>(h_bf, w2t, y2);
    spmm2_lsm_kernel<<<N_NODES / 4, 256, 0, stream>>>(cursor, sortedP, y2, b2, out);
}